// Round 1
// baseline (573.737 us; speedup 1.0000x reference)
//
#include <hip/hip_runtime.h>
#include <stdint.h>

typedef unsigned long long u64;
typedef uint32_t u32;

#define BB  32
#define CC  256
#define HH  56
#define WW  56
#define OHH 28
#define OWW 28
#define NPIX (BB*OHH*OWW)   // 25088

// ---------------- Kernel 0: weight prep (alpha + bit-pack) ----------------
// blocks 0..255: w1 (co = blockIdx), 9 taps per ci; blocks 256..511: w2.
// Bit convention: word j covers channels 32j..32j+31, bit b = ch%32, bit=1 iff w>0.
__global__ __launch_bounds__(256) void rrb_prep_w(const float* __restrict__ w1,
                                                  const float* __restrict__ w2,
                                                  u32* __restrict__ wp1, u32* __restrict__ wp2,
                                                  float* __restrict__ alpha1, float* __restrict__ alpha2) {
    __shared__ float red[256];
    int co = blockIdx.x & 255;
    int t = threadIdx.x;            // ci
    int wid = t >> 6, lane = t & 63;
    float asum = 0.f;
    if (blockIdx.x < 256) {
        const float* wr = w1 + (size_t)co * 2304 + (size_t)t * 9;
        float v[9];
        #pragma unroll
        for (int k = 0; k < 9; ++k) { v[k] = wr[k]; asum += fabsf(v[k]); }
        #pragma unroll
        for (int k = 0; k < 9; ++k) {
            u64 m = __ballot(v[k] > 0.f);
            if (lane == 0)
                *(u64*)&wp1[((size_t)co * 9 + k) * 8 + 2 * wid] = m;
        }
    } else {
        float v = w2[co * 256 + t];
        asum = fabsf(v);
        u64 m = __ballot(v > 0.f);
        if (lane == 0) *(u64*)&wp2[co * 8 + 2 * wid] = m;
    }
    red[t] = asum; __syncthreads();
    for (int st = 128; st > 0; st >>= 1) {
        if (t < st) red[t] += red[t + st];
        __syncthreads();
    }
    if (t == 0) {
        if (blockIdx.x < 256) alpha1[co] = red[0] / 2304.f;
        else                  alpha2[co] = red[0] / 256.f;
    }
}

// ---------------- Kernel 1: pack sign(x+beta1) bits + 2x2 avgpool ----------------
// One block per (n, oh). thread = channel. Wave ballots build the bitwords.
__global__ __launch_bounds__(256) void rrb_pack_x(const float* __restrict__ x,
                                                  const float* __restrict__ rsb1,
                                                  u32* __restrict__ xb, float* __restrict__ pool) {
    int blk = blockIdx.x;
    int n = blk / OHH, oh = blk - n * OHH;
    int c = threadIdx.x;
    int wid = c >> 6, lane = c & 63;
    float beta = rsb1[c];
    const float* xr0 = x + ((size_t)(n * CC + c) * HH + 2 * oh) * WW;
    const float* xr1 = xr0 + WW;
    float* pr = pool + ((size_t)(n * CC + c) * OHH + oh) * OWW;
    u32* xb0 = xb + ((size_t)(n * HH + 2 * oh) * WW) * 8;
    u32* xb1 = xb0 + WW * 8;
    for (int ow = 0; ow < OWW; ++ow) {
        float2 r0 = *(const float2*)&xr0[2 * ow];
        float2 r1 = *(const float2*)&xr1[2 * ow];
        pr[ow] = (r0.x + r0.y + r1.x + r1.y) * 0.25f;
        u64 m0 = __ballot(r0.x + beta > 0.f);
        u64 m1 = __ballot(r0.y + beta > 0.f);
        u64 m2 = __ballot(r1.x + beta > 0.f);
        u64 m3 = __ballot(r1.y + beta > 0.f);
        if (lane == 0) {
            *(u64*)&xb0[(2 * ow    ) * 8 + 2 * wid] = m0;
            *(u64*)&xb0[(2 * ow + 1) * 8 + 2 * wid] = m1;
            *(u64*)&xb1[(2 * ow    ) * 8 + 2 * wid] = m2;
            *(u64*)&xb1[(2 * ow + 1) * 8 + 2 * wid] = m3;
        }
    }
}

// ---------------- Kernel 2: binary conv1 (3x3, stride 2, pad 1) + bn1 stats ----------------
// One block per (n, oh). thread = output channel. x bitwords staged in LDS (broadcast reads),
// weight bitwords (72 u32) held in registers. Exact integer sums -> int16 out + int stats.
__global__ __launch_bounds__(256) void rrb_conv1(const u32* __restrict__ xb,
                                                 const u32* __restrict__ wp1,
                                                 short* __restrict__ S1,
                                                 int* __restrict__ s_sum, u64* __restrict__ s_sq) {
    __shared__ u32 xs[3 * WW * 8];   // 5.25 KB
    int blk = blockIdx.x;
    int n = blk / OHH, oh = blk - n * OHH;
    int t = threadIdx.x;             // co
    int r0 = 2 * oh - 1;
    for (int i = t; i < 3 * WW * 8; i += 256) {
        int row = i / (WW * 8);
        int ih = r0 + row;           // ih <= 55 always; ih<0 only for oh==0,row==0
        xs[i] = (ih >= 0) ? xb[((size_t)(n * HH + ih) * WW) * 8 + (i - row * WW * 8)] : 0u;
    }
    u32 wreg[72];
    {
        const u32* wsrc = wp1 + (size_t)t * 72;
        #pragma unroll
        for (int i = 0; i < 72; ++i) wreg[i] = wsrc[i];
    }
    __syncthreads();
    bool oh0 = (oh == 0);
    int bsum = 0; long long bsq = 0;
    short* out = S1 + ((size_t)(n * CC + t) * OHH + oh) * OWW;
    for (int ow = 0; ow < OWW; ++ow) {
        int S = 0;
        #pragma unroll
        for (int kh = 0; kh < 3; ++kh) {
            bool vkh = !(kh == 0 && oh0);
            #pragma unroll
            for (int kw = 0; kw < 3; ++kw) {
                int iw = 2 * ow + kw - 1;
                bool ok = vkh && (iw >= 0);
                int iwc = iw < 0 ? 0 : iw;
                const u32* xp = &xs[(kh * WW + iwc) * 8];
                int p = 0;
                #pragma unroll
                for (int j = 0; j < 8; ++j) p += __popc(xp[j] ^ wreg[(kh * 3 + kw) * 8 + j]);
                S += ok ? (256 - 2 * p) : 0;
            }
        }
        out[ow] = (short)S;
        bsum += S;
        bsq += (long long)S * S;
    }
    atomicAdd(&s_sum[t], bsum);
    atomicAdd(&s_sq[t], (u64)bsq);
}

// ---------------- Kernel 3/6: finalize BN params from exact integer stats ----------------
// conv_out = alpha*S;  bn(conv_out) = A*S + Bv  with A = alpha*gamma*rsqrt(var+eps).
__global__ void rrb_finalize(const int* __restrict__ ssum, const u64* __restrict__ ssq,
                             const float* __restrict__ alpha,
                             const float* __restrict__ gamma, const float* __restrict__ beta,
                             float* __restrict__ A, float* __restrict__ Bv) {
    int c = threadIdx.x;
    const double N = (double)NPIX;
    double s = (double)ssum[c];
    double q = (double)ssq[c];
    double mS = s / N;
    double vS = q / N - mS * mS;
    double al = (double)alpha[c];
    double mean = al * mS;
    double var = al * al * vS;
    double scale = (double)gamma[c] / sqrt(var + 1e-5);
    A[c] = (float)(al * scale);
    Bv[c] = (float)((double)beta[c] - mean * scale);
}

// ---------------- Kernel 4: out1 = rprelu(bn1(conv1)+pool), pack sign(out1+beta2) ----------
// In-place: overwrites pool buffer with out1.
__global__ __launch_bounds__(256) void rrb_out1(const short* __restrict__ S1,
                                                float* __restrict__ pool,
                                                const float* __restrict__ A1, const float* __restrict__ B1,
                                                const float* __restrict__ pg, const float* __restrict__ pz,
                                                const float* __restrict__ ps, const float* __restrict__ rsb2,
                                                u32* __restrict__ x2b) {
    int blk = blockIdx.x;
    int n = blk / OHH, oh = blk - n * OHH;
    int c = threadIdx.x;
    int wid = c >> 6, lane = c & 63;
    float a = A1[c], b = B1[c];
    float g = pg[c], z = pz[c], s = ps[c], b2 = rsb2[c];
    const short* sp = S1 + ((size_t)(n * CC + c) * OHH + oh) * OWW;
    float* pp = pool + ((size_t)(n * CC + c) * OHH + oh) * OWW;
    u32* xo = x2b + ((size_t)(n * OHH + oh) * OWW) * 8;
    for (int ow = 0; ow < OWW; ++ow) {
        float v = a * (float)sp[ow] + b + pp[ow];
        float xsv = v - g;
        float o = (xsv > 0.f ? xsv : s * xsv) + z;
        pp[ow] = o;
        u64 m = __ballot(o + b2 > 0.f);
        if (lane == 0) *(u64*)&xo[ow * 8 + 2 * wid] = m;
    }
}

// ---------------- Kernel 5: binary conv2 (1x1) + bn2 stats ----------------
__global__ __launch_bounds__(256) void rrb_conv2(const u32* __restrict__ x2b,
                                                 const u32* __restrict__ wp2,
                                                 short* __restrict__ S2,
                                                 int* __restrict__ s_sum, u64* __restrict__ s_sq) {
    __shared__ u32 xs[OWW * 8];      // 896 B
    int blk = blockIdx.x;
    int n = blk / OHH, oh = blk - n * OHH;
    int t = threadIdx.x;             // co
    const u32* src = x2b + ((size_t)(n * OHH + oh) * OWW) * 8;
    if (t < OWW * 8) xs[t] = src[t];
    u32 wr[8];
    {
        const u32* wsv = wp2 + (size_t)t * 8;
        #pragma unroll
        for (int j = 0; j < 8; ++j) wr[j] = wsv[j];
    }
    __syncthreads();
    int bsum = 0; long long bsq = 0;
    short* out = S2 + ((size_t)(n * CC + t) * OHH + oh) * OWW;
    for (int ow = 0; ow < OWW; ++ow) {
        int p = 0;
        #pragma unroll
        for (int j = 0; j < 8; ++j) p += __popc(xs[ow * 8 + j] ^ wr[j]);
        int S = 256 - 2 * p;
        out[ow] = (short)S;
        bsum += S;
        bsq += (long long)S * S;
    }
    atomicAdd(&s_sum[t], bsum);
    atomicAdd(&s_sq[t], (u64)bsq);
}

// ---------------- Kernel 7: y = bn2(conv2) + out1, write concat twice ----------------
__global__ __launch_bounds__(256) void rrb_final(const short* __restrict__ S2,
                                                 const float* __restrict__ out1,
                                                 const float* __restrict__ A2, const float* __restrict__ B2,
                                                 float* __restrict__ y) {
    int i = blockIdx.x * 256 + threadIdx.x;  // flat over B*C*OH*OW = 6422528
    int c = (i / (OHH * OWW)) % CC;
    int n = i / (CC * OHH * OWW);
    int hw = i % (OHH * OWW);
    float v = A2[c] * (float)S2[i] + B2[c] + out1[i];
    size_t o = ((size_t)n * (2 * CC) + c) * (OHH * OWW) + hw;
    y[o] = v;
    y[o + (size_t)CC * OHH * OWW] = v;
}

extern "C" void kernel_launch(void* const* d_in, const int* in_sizes, int n_in,
                              void* d_out, int out_size, void* d_ws, size_t ws_size,
                              hipStream_t stream) {
    const float* x    = (const float*)d_in[0];
    const float* rsb1 = (const float*)d_in[1];
    const float* w1   = (const float*)d_in[2];
    const float* bn1g = (const float*)d_in[3];
    const float* bn1b = (const float*)d_in[4];
    const float* rsb2 = (const float*)d_in[5];
    const float* w2   = (const float*)d_in[6];
    const float* bn2g = (const float*)d_in[7];
    const float* bn2b = (const float*)d_in[8];
    const float* pg   = (const float*)d_in[9];
    const float* pz   = (const float*)d_in[10];
    const float* ps   = (const float*)d_in[11];
    float* y = (float*)d_out;

    char* ws = (char*)d_ws;
    if (ws_size < 55488512) return;   // need ~55.5 MB of scratch

    u32*   wp1    = (u32*)(ws + 0);          // 73728 B
    u32*   wp2    = (u32*)(ws + 73728);      // 8192 B
    float* alpha1 = (float*)(ws + 81920);
    float* alpha2 = (float*)(ws + 82944);
    float* A1     = (float*)(ws + 83968);
    float* B1     = (float*)(ws + 84992);
    float* A2     = (float*)(ws + 86016);
    float* B2     = (float*)(ws + 87040);
    int*   st1_sum = (int*)(ws + 88064);     // 1024 B
    u64*   st1_sq  = (u64*)(ws + 89088);     // 2048 B
    int*   st2_sum = (int*)(ws + 91136);     // 1024 B
    u64*   st2_sq  = (u64*)(ws + 92160);     // 2048 B
    u32*   xb   = (u32*)(ws + 94208);        // 3,211,264 B
    float* pool = (float*)(ws + 3305472);    // 25,690,112 B (becomes out1 in-place)
    short* S1   = (short*)(ws + 28995584);   // 12,845,056 B
    u32*   x2b  = (u32*)(ws + 41840640);     // 802,816 B
    short* S2   = (short*)(ws + 42643456);   // 12,845,056 B -> end 55,488,512

    // stats must be zeroed every call (atomics accumulate)
    hipMemsetAsync(ws + 88064, 0, 6144, stream);

    rrb_prep_w<<<512, 256, 0, stream>>>(w1, w2, wp1, wp2, alpha1, alpha2);
    rrb_pack_x<<<BB * OHH, 256, 0, stream>>>(x, rsb1, xb, pool);
    rrb_conv1<<<BB * OHH, 256, 0, stream>>>(xb, wp1, S1, st1_sum, st1_sq);
    rrb_finalize<<<1, 256, 0, stream>>>(st1_sum, st1_sq, alpha1, bn1g, bn1b, A1, B1);
    rrb_out1<<<BB * OHH, 256, 0, stream>>>(S1, pool, A1, B1, pg, pz, ps, rsb2, x2b);
    rrb_conv2<<<BB * OHH, 256, 0, stream>>>(x2b, wp2, S2, st2_sum, st2_sq);
    rrb_finalize<<<1, 256, 0, stream>>>(st2_sum, st2_sq, alpha2, bn2g, bn2b, A2, B2);
    rrb_final<<<(BB * CC * OHH * OWW) / 256, 256, 0, stream>>>(S2, pool, A2, B2, y);
}

// Round 2
// 185.259 us; speedup vs baseline: 3.0969x; 3.0969x over previous
//
#include <hip/hip_runtime.h>
#include <stdint.h>

typedef unsigned long long u64;
typedef uint32_t u32;

#define BB  32
#define CC  256
#define HH  56
#define WW  56
#define OHH 28
#define OWW 28
#define NPIX (BB*OHH*OWW)   // 25088

// ---------------- Kernel 0: weight prep (alpha + bit-pack) ----------------
__global__ __launch_bounds__(256) void rrb_prep_w(const float* __restrict__ w1,
                                                  const float* __restrict__ w2,
                                                  u32* __restrict__ wp1, u32* __restrict__ wp2,
                                                  float* __restrict__ alpha1, float* __restrict__ alpha2) {
    __shared__ float red[256];
    int co = blockIdx.x & 255;
    int t = threadIdx.x;            // ci
    int wid = t >> 6, lane = t & 63;
    float asum = 0.f;
    if (blockIdx.x < 256) {
        const float* wr = w1 + (size_t)co * 2304 + (size_t)t * 9;
        float v[9];
        #pragma unroll
        for (int k = 0; k < 9; ++k) { v[k] = wr[k]; asum += fabsf(v[k]); }
        #pragma unroll
        for (int k = 0; k < 9; ++k) {
            u64 m = __ballot(v[k] > 0.f);
            if (lane == 0)
                *(u64*)&wp1[((size_t)co * 9 + k) * 8 + 2 * wid] = m;
        }
    } else {
        float v = w2[co * 256 + t];
        asum = fabsf(v);
        u64 m = __ballot(v > 0.f);
        if (lane == 0) *(u64*)&wp2[co * 8 + 2 * wid] = m;
    }
    red[t] = asum; __syncthreads();
    for (int st = 128; st > 0; st >>= 1) {
        if (t < st) red[t] += red[t + st];
        __syncthreads();
    }
    if (t == 0) {
        if (blockIdx.x < 256) alpha1[co] = red[0] / 2304.f;
        else                  alpha2[co] = red[0] / 256.f;
    }
}

// ---------------- Kernel 1: pack sign(x+beta1) bits + 2x2 avgpool (coalesced) ----------------
// Thread = (n, oh, ow, word j). Loops the 32 channels of its word over a 2x2 pixel quad.
// Lane layout: j fastest (8 j-lanes share a pixel quad) -> xb word-writes cover full 64B sectors;
// x float2 loads form 8x 64B segments per wave. Pool stored CHANNEL-LAST [pix][256].
__global__ __launch_bounds__(256) void rrb_pack_x(const float* __restrict__ x,
                                                  const float* __restrict__ rsb1,
                                                  u32* __restrict__ xb, float* __restrict__ pool) {
    int i = blockIdx.x * 256 + threadIdx.x;   // 32*28*28*8 = 200704 threads
    int j  = i & 7;
    int t2 = i >> 3;
    int ow = t2 % OWW;
    t2 /= OWW;
    int oh = t2 % OHH;
    int n  = t2 / OHH;
    const float* base = x + (((size_t)(n * CC + 32 * j) * HH + 2 * oh) * WW + 2 * ow);
    u32 w00 = 0, w01 = 0, w10 = 0, w11 = 0;
    float* pp = pool + ((size_t)(n * OHH + oh) * OWW + ow) * CC + 32 * j;
    #pragma unroll
    for (int q = 0; q < 8; ++q) {
        float pv[4];
        #pragma unroll
        for (int r = 0; r < 4; ++r) {
            int cc = 4 * q + r;
            const float* p = base + (size_t)cc * (HH * WW);
            float2 r0 = *(const float2*)p;
            float2 r1 = *(const float2*)(p + WW);
            float beta = rsb1[32 * j + cc];
            w00 |= (u32)(r0.x + beta > 0.f) << cc;
            w01 |= (u32)(r0.y + beta > 0.f) << cc;
            w10 |= (u32)(r1.x + beta > 0.f) << cc;
            w11 |= (u32)(r1.y + beta > 0.f) << cc;
            pv[r] = (r0.x + r0.y + r1.x + r1.y) * 0.25f;
        }
        *(float4*)&pp[4 * q] = make_float4(pv[0], pv[1], pv[2], pv[3]);
    }
    u32* xo = xb + (((size_t)(n * HH + 2 * oh) * WW + 2 * ow) * 8) + j;
    xo[0] = w00;
    xo[8] = w01;
    xo[WW * 8] = w10;
    xo[WW * 8 + 8] = w11;
}

// ---------------- Kernel 2: binary conv1 (3x3, s2, p1) + bn1 stats ----------------
// Block (n, oh), thread = co. S1 stored CHANNEL-LAST [pix][256] -> coalesced writes.
__global__ __launch_bounds__(256) void rrb_conv1(const u32* __restrict__ xb,
                                                 const u32* __restrict__ wp1,
                                                 short* __restrict__ S1,
                                                 int* __restrict__ s_sum, u64* __restrict__ s_sq) {
    __shared__ u32 xs[3 * WW * 8];   // 5.25 KB
    int blk = blockIdx.x;
    int n = blk / OHH, oh = blk - n * OHH;
    int t = threadIdx.x;             // co
    int r0 = 2 * oh - 1;
    for (int i = t; i < 3 * WW * 8; i += 256) {
        int row = i / (WW * 8);
        int ih = r0 + row;
        xs[i] = (ih >= 0) ? xb[((size_t)(n * HH + ih) * WW) * 8 + (i - row * WW * 8)] : 0u;
    }
    u32 wreg[72];
    {
        const u32* wsrc = wp1 + (size_t)t * 72;
        #pragma unroll
        for (int i = 0; i < 72; ++i) wreg[i] = wsrc[i];
    }
    __syncthreads();
    bool oh0 = (oh == 0);
    int bsum = 0; long long bsq = 0;
    short* outp = S1 + ((size_t)(n * OHH + oh) * OWW) * CC + t;
    for (int ow = 0; ow < OWW; ++ow) {
        int S = 0;
        #pragma unroll
        for (int kh = 0; kh < 3; ++kh) {
            bool vkh = !(kh == 0 && oh0);
            #pragma unroll
            for (int kw = 0; kw < 3; ++kw) {
                int iw = 2 * ow + kw - 1;
                bool ok = vkh && (iw >= 0);
                int iwc = iw < 0 ? 0 : iw;
                const u32* xp = &xs[(kh * WW + iwc) * 8];
                int p = 0;
                #pragma unroll
                for (int j = 0; j < 8; ++j) p += __popc(xp[j] ^ wreg[(kh * 3 + kw) * 8 + j]);
                S += ok ? (256 - 2 * p) : 0;
            }
        }
        outp[ow * CC] = (short)S;
        bsum += S;
        bsq += (long long)S * S;
    }
    atomicAdd(&s_sum[t], bsum);
    atomicAdd(&s_sq[t], (u64)bsq);
}

// ---------------- Kernel 3/6: finalize BN params from exact integer stats ----------------
__global__ void rrb_finalize(const int* __restrict__ ssum, const u64* __restrict__ ssq,
                             const float* __restrict__ alpha,
                             const float* __restrict__ gamma, const float* __restrict__ beta,
                             float* __restrict__ A, float* __restrict__ Bv) {
    int c = threadIdx.x;
    const double N = (double)NPIX;
    double s = (double)ssum[c];
    double q = (double)ssq[c];
    double mS = s / N;
    double vS = q / N - mS * mS;
    double al = (double)alpha[c];
    double mean = al * mS;
    double var = al * al * vS;
    double scale = (double)gamma[c] / sqrt(var + 1e-5);
    A[c] = (float)(al * scale);
    Bv[c] = (float)((double)beta[c] - mean * scale);
}

// ---------------- Kernel 4: out1 = rprelu(bn1+pool), pack sign(out1+beta2) ----------------
// Block (n, oh), thread = c. All tensors channel-last -> every access coalesced.
// In-place over pool. Ballot (thread=c) builds x2b words.
__global__ __launch_bounds__(256) void rrb_out1(const short* __restrict__ S1,
                                                float* __restrict__ pool,
                                                const float* __restrict__ A1, const float* __restrict__ B1,
                                                const float* __restrict__ pg, const float* __restrict__ pz,
                                                const float* __restrict__ ps, const float* __restrict__ rsb2,
                                                u32* __restrict__ x2b) {
    int blk = blockIdx.x;
    int n = blk / OHH, oh = blk - n * OHH;
    int c = threadIdx.x;
    int wid = c >> 6, lane = c & 63;
    float a = A1[c], b = B1[c];
    float g = pg[c], z = pz[c], s = ps[c], b2 = rsb2[c];
    const short* sp = S1 + ((size_t)(n * OHH + oh) * OWW) * CC + c;
    float* pp = pool + ((size_t)(n * OHH + oh) * OWW) * CC + c;
    u32* xo = x2b + ((size_t)(n * OHH + oh) * OWW) * 8;
    for (int ow = 0; ow < OWW; ++ow) {
        float v = a * (float)sp[ow * CC] + b + pp[ow * CC];
        float xsv = v - g;
        float o = (xsv > 0.f ? xsv : s * xsv) + z;
        pp[ow * CC] = o;
        u64 m = __ballot(o + b2 > 0.f);
        if (lane == 0) *(u64*)&xo[ow * 8 + 2 * wid] = m;
    }
}

// ---------------- Kernel 5: binary conv2 (1x1) + bn2 stats ----------------
__global__ __launch_bounds__(256) void rrb_conv2(const u32* __restrict__ x2b,
                                                 const u32* __restrict__ wp2,
                                                 short* __restrict__ S2,
                                                 int* __restrict__ s_sum, u64* __restrict__ s_sq) {
    __shared__ u32 xs[OWW * 8];      // 896 B
    int blk = blockIdx.x;
    int n = blk / OHH, oh = blk - n * OHH;
    int t = threadIdx.x;             // co
    const u32* src = x2b + ((size_t)(n * OHH + oh) * OWW) * 8;
    if (t < OWW * 8) xs[t] = src[t];
    u32 wr[8];
    {
        const u32* wsv = wp2 + (size_t)t * 8;
        #pragma unroll
        for (int j = 0; j < 8; ++j) wr[j] = wsv[j];
    }
    __syncthreads();
    int bsum = 0; long long bsq = 0;
    short* outp = S2 + ((size_t)(n * OHH + oh) * OWW) * CC + t;
    for (int ow = 0; ow < OWW; ++ow) {
        int p = 0;
        #pragma unroll
        for (int j = 0; j < 8; ++j) p += __popc(xs[ow * 8 + j] ^ wr[j]);
        int S = 256 - 2 * p;
        outp[ow * CC] = (short)S;
        bsum += S;
        bsq += (long long)S * S;
    }
    atomicAdd(&s_sum[t], bsum);
    atomicAdd(&s_sq[t], (u64)bsq);
}

// ---------------- Kernel 7: y = bn2(conv2) + out1, concat duplicate, NCHW transpose ------
// Block (n, oh), thread = c. Reads channel-last coalesced; buffers a 28-float row in
// registers, writes 7 aligned float4 per half.
__global__ __launch_bounds__(256) void rrb_final(const short* __restrict__ S2,
                                                 const float* __restrict__ out1,
                                                 const float* __restrict__ A2, const float* __restrict__ B2,
                                                 float* __restrict__ y) {
    int blk = blockIdx.x;
    int n = blk / OHH, oh = blk - n * OHH;
    int c = threadIdx.x;
    float a = A2[c], b = B2[c];
    const short* sp = S2 + ((size_t)(n * OHH + oh) * OWW) * CC + c;
    const float* op = out1 + ((size_t)(n * OHH + oh) * OWW) * CC + c;
    float buf[OWW];
    #pragma unroll
    for (int ow = 0; ow < OWW; ++ow)
        buf[ow] = a * (float)sp[ow * CC] + b + op[ow * CC];
    float* y0 = y + ((size_t)(n * 2 * CC + c) * OHH + oh) * OWW;
    float* y1 = y0 + (size_t)CC * OHH * OWW;
    #pragma unroll
    for (int k = 0; k < OWW / 4; ++k) {
        float4 v = make_float4(buf[4 * k], buf[4 * k + 1], buf[4 * k + 2], buf[4 * k + 3]);
        *(float4*)&y0[4 * k] = v;
        *(float4*)&y1[4 * k] = v;
    }
}

extern "C" void kernel_launch(void* const* d_in, const int* in_sizes, int n_in,
                              void* d_out, int out_size, void* d_ws, size_t ws_size,
                              hipStream_t stream) {
    const float* x    = (const float*)d_in[0];
    const float* rsb1 = (const float*)d_in[1];
    const float* w1   = (const float*)d_in[2];
    const float* bn1g = (const float*)d_in[3];
    const float* bn1b = (const float*)d_in[4];
    const float* rsb2 = (const float*)d_in[5];
    const float* w2   = (const float*)d_in[6];
    const float* bn2g = (const float*)d_in[7];
    const float* bn2b = (const float*)d_in[8];
    const float* pg   = (const float*)d_in[9];
    const float* pz   = (const float*)d_in[10];
    const float* ps   = (const float*)d_in[11];
    float* y = (float*)d_out;

    char* ws = (char*)d_ws;
    if (ws_size < 55488512) return;

    u32*   wp1    = (u32*)(ws + 0);          // 73728 B
    u32*   wp2    = (u32*)(ws + 73728);      // 8192 B
    float* alpha1 = (float*)(ws + 81920);
    float* alpha2 = (float*)(ws + 82944);
    float* A1     = (float*)(ws + 83968);
    float* B1     = (float*)(ws + 84992);
    float* A2     = (float*)(ws + 86016);
    float* B2     = (float*)(ws + 87040);
    int*   st1_sum = (int*)(ws + 88064);
    u64*   st1_sq  = (u64*)(ws + 89088);
    int*   st2_sum = (int*)(ws + 91136);
    u64*   st2_sq  = (u64*)(ws + 92160);
    u32*   xb   = (u32*)(ws + 94208);        // 3,211,264 B   [n][h][w][8]
    float* pool = (float*)(ws + 3305472);    // 25,690,112 B  [pix][256] (becomes out1)
    short* S1   = (short*)(ws + 28995584);   // 12,845,056 B  [pix][256]
    u32*   x2b  = (u32*)(ws + 41840640);     // 802,816 B     [pix][8]
    short* S2   = (short*)(ws + 42643456);   // 12,845,056 B  [pix][256]

    hipMemsetAsync(ws + 88064, 0, 6144, stream);

    rrb_prep_w<<<512, 256, 0, stream>>>(w1, w2, wp1, wp2, alpha1, alpha2);
    rrb_pack_x<<<(BB * OHH * OWW * 8) / 256, 256, 0, stream>>>(x, rsb1, xb, pool);
    rrb_conv1<<<BB * OHH, 256, 0, stream>>>(xb, wp1, S1, st1_sum, st1_sq);
    rrb_finalize<<<1, 256, 0, stream>>>(st1_sum, st1_sq, alpha1, bn1g, bn1b, A1, B1);
    rrb_out1<<<BB * OHH, 256, 0, stream>>>(S1, pool, A1, B1, pg, pz, ps, rsb2, x2b);
    rrb_conv2<<<BB * OHH, 256, 0, stream>>>(x2b, wp2, S2, st2_sum, st2_sq);
    rrb_finalize<<<1, 256, 0, stream>>>(st2_sum, st2_sq, alpha2, bn2g, bn2b, A2, B2);
    rrb_final<<<BB * OHH, 256, 0, stream>>>(S2, pool, A2, B2, y);
}